// Round 9
// baseline (453.926 us; speedup 1.0000x reference)
//
#include <hip/hip_runtime.h>
#include <math.h>

#define N_ROWS 65536
#define Q 4096
#define E 64
#define CT 64                 // codes staged per tile-step
#define NTS_H 32              // tile-steps per half (2048 codes)
#define MARGIN 0.25f
#define CAPH 4                // candidate cap per (row, half)
#define FLAGBIT 0x40000000
#define KMASK 0xFFFFF000u

typedef short s8v __attribute__((ext_vector_type(8)));   // 8 bf16 (4 VGPRs)
typedef float f4v __attribute__((ext_vector_type(4)));   // 4 fp32 acc

static __device__ __forceinline__ unsigned umin_(unsigned a, unsigned b) {
  return __builtin_elementwise_min(a, b);   // v_min_u32
}
static __device__ __forceinline__ unsigned umax_(unsigned a, unsigned b) {
  return __builtin_elementwise_max(a, b);   // v_max_u32
}

// ---------- exact-arithmetic helpers (validated absmax=0 rounds 1-8) ----------
__device__ __forceinline__ float pairwise_sq_sum64(const float* v) {
#pragma clang fp contract(off)
  float r[8];
#pragma unroll
  for (int j = 0; j < 8; ++j) r[j] = v[j] * v[j];
#pragma unroll
  for (int i = 8; i < 64; i += 8) {
#pragma unroll
    for (int j = 0; j < 8; ++j) {
      float p = v[i + j] * v[i + j];
      r[j] = r[j] + p;
    }
  }
  return ((r[0] + r[1]) + (r[2] + r[3])) + ((r[4] + r[5]) + (r[6] + r[7]));
}

__device__ __forceinline__ void load_row64(const float* __restrict__ src,
                                           float* dst) {
  const float4* p = (const float4*)src;
#pragma unroll
  for (int k4 = 0; k4 < 16; ++k4) {
    const float4 t = p[k4];
    dst[4 * k4 + 0] = t.x;
    dst[4 * k4 + 1] = t.y;
    dst[4 * k4 + 2] = t.z;
    dst[4 * k4 + 3] = t.w;
  }
}

// exact distance, reference-bitwise: sequential fmaf k ascending,
// RN(hsq+wsq), fmaf(-2,...)
__device__ __forceinline__ float exact_dist(const float* hv, float hs,
                                            const float* __restrict__ w,
                                            float wsqc, int c) {
  const float* wr = w + (size_t)c * E;
  float dot = 0.f;
#pragma unroll
  for (int k = 0; k < E; ++k) dot = fmaf(wr[k], hv[k], dot);
  return fmaf(-2.f, dot, hs + wsqc);
}

__device__ __forceinline__ unsigned short bf16_rn(float f) {
  unsigned int u = __float_as_uint(f);
  u += 0x7FFFu + ((u >> 16) & 1u);
  return (unsigned short)(u >> 16);
}
__device__ __forceinline__ float bf16_to_f(unsigned short s) {
  return __uint_as_float(((unsigned int)s) << 16);
}

// ---------- fused prep: blocks 0..15 -> w path (+wT), 16..271 -> x path ------
__global__ __launch_bounds__(256) void prep_kernel(
    const float* __restrict__ w, const float* __restrict__ x,
    float* __restrict__ wsq, float* __restrict__ hsq,
    short* __restrict__ whiS, short* __restrict__ wloS,
    float* __restrict__ wT, int* __restrict__ cntFlag,
    int* __restrict__ ovfCnt) {
  if (blockIdx.x < 16) {
    const int q = blockIdx.x * 256 + threadIdx.x;
    if (q == 0) *ovfCnt = 0;
    float v[E];
    load_row64(w + (size_t)q * E, v);
    wsq[q] = pairwise_sq_sum64(v);
#pragma unroll
    for (int k = 0; k < E; ++k) wT[(size_t)k * Q + q] = v[k];
    const int T = q >> 6, code_in = q & 63;
#pragma unroll
    for (int ch = 0; ch < 8; ++ch) {
      s8v hi, lo;
#pragma unroll
      for (int j = 0; j < 8; ++j) {
        const float f = v[ch * 8 + j];
        const unsigned short h = bf16_rn(f);
        const float resid = f - bf16_to_f(h);
        hi[j] = (short)h;
        lo[j] = (short)bf16_rn(resid);
      }
      const size_t base = (size_t)T * 4096 + ((size_t)(ch * 64 + code_in)) * 8;
      *(s8v*)&whiS[base] = hi;
      *(s8v*)&wloS[base] = lo;
    }
  } else {
    const int n = (blockIdx.x - 16) * 256 + threadIdx.x;
    float v[E];
    load_row64(x + (size_t)n * E, v);
    hsq[n] = pairwise_sq_sum64(v);
    cntFlag[n] = 0;            // ws is re-poisoned each launch: must zero
    cntFlag[N_ROWS + n] = 0;
  }
}

// ---------- main: MFMA screen over one Q-half, packed branchless top-3 -------
// grid = 1024: block b -> rows [(b>>1)*128, +128), half h = b&1 (2048 codes).
// 4 blocks/CU (LDS 33 KB), 16 waves/CU.
__global__ __launch_bounds__(256, 4) void dist_kernel(
    const float* __restrict__ x, const short* __restrict__ whiS,
    const short* __restrict__ wloS, const float* __restrict__ wsq,
    const float* __restrict__ hsq, int* __restrict__ cntFlag,
    int* __restrict__ lists) {
  __shared__ short BsHi[2][CT * 64];   // 2 x 8 KB (double-buffered)
  __shared__ short BsLo[2][CT * 64];   // 2 x 8 KB
  __shared__ float WsS[2][CT];

  const int tid = threadIdx.x;
  const int wv = tid >> 6;
  const int lane = tid & 63;
  const int n = lane & 15;
  const int quad = lane >> 4;
  const int h = blockIdx.x & 1;
  const int rowBase = (blockIdx.x >> 1) * 128;
  const int ts0 = h * NTS_H;

  // ---- A-frags: a = -2x, split hi/lo, built once ----
  s8v ahi[2][2], alo[2][2];  // [rowtile][ks]
#pragma unroll
  for (int rt = 0; rt < 2; ++rt) {
#pragma unroll
    for (int ks = 0; ks < 2; ++ks) {
      const int gRow = rowBase + wv * 32 + rt * 16 + n;
      const float* xp = x + (size_t)gRow * E + ks * 32 + quad * 8;
      const float4 v0 = ((const float4*)xp)[0];
      const float4 v1 = ((const float4*)xp)[1];
      float vals[8] = {v0.x, v0.y, v0.z, v0.w, v1.x, v1.y, v1.z, v1.w};
      s8v hi, lo;
#pragma unroll
      for (int j = 0; j < 8; ++j) {
        const float a = -2.f * vals[j];
        const unsigned short hb = bf16_rn(a);
        hi[j] = (short)hb;
        lo[j] = (short)bf16_rn(a - bf16_to_f(hb));
      }
      ahi[rt][ks] = hi;
      alo[rt][ks] = lo;
    }
  }

  // hsq + 4.0 offset folded into C-init (keeps packed floats positive)
  float hsqv4[2][4];
#pragma unroll
  for (int rt = 0; rt < 2; ++rt)
#pragma unroll
    for (int r = 0; r < 4; ++r)
      hsqv4[rt][r] = hsq[rowBase + wv * 32 + rt * 16 + quad * 4 + r] + 4.0f;

  // branchless packed top-3 per (rowtile, r): key = (bits(d+4)&KMASK)|code
  unsigned int m0[2][4], m1[2][4], m2[2][4];
#pragma unroll
  for (int rt = 0; rt < 2; ++rt)
#pragma unroll
    for (int r = 0; r < 4; ++r) {
      m0[rt][r] = 0xFFFFFFFFu;
      m1[rt][r] = 0xFFFFFFFFu;
      m2[rt][r] = 0xFFFFFFFFu;
    }

  // ---- prefetch ts0 into registers ----
  int4 pH0, pH1, pL0, pL1;
  float pW;
  {
    const int4* gh = (const int4*)(whiS + (size_t)ts0 * 4096);
    const int4* gl = (const int4*)(wloS + (size_t)ts0 * 4096);
    pH0 = gh[tid];
    pH1 = gh[tid + 256];
    pL0 = gl[tid];
    pL1 = gl[tid + 256];
    pW = (tid < CT) ? wsq[ts0 * CT + tid] : 0.f;
  }

#pragma unroll 1
  for (int ts = ts0; ts < ts0 + NTS_H; ++ts) {
    const int buf = ts & 1;
    ((int4*)&BsHi[buf][0])[tid] = pH0;
    ((int4*)&BsHi[buf][0])[tid + 256] = pH1;
    ((int4*)&BsLo[buf][0])[tid] = pL0;
    ((int4*)&BsLo[buf][0])[tid + 256] = pL1;
    if (tid < CT) WsS[buf][tid] = pW;
    __syncthreads();  // single barrier per ts
    if (ts + 1 < ts0 + NTS_H) {
      const int4* gh = (const int4*)(whiS + (size_t)(ts + 1) * 4096);
      const int4* gl = (const int4*)(wloS + (size_t)(ts + 1) * 4096);
      pH0 = gh[tid];
      pH1 = gh[tid + 256];
      pL0 = gl[tid];
      pL1 = gl[tid + 256];
      if (tid < CT) pW = wsq[(ts + 1) * CT + tid];
    }

#pragma unroll
    for (int ct = 0; ct < 4; ++ct) {
      const s8v bhi0 = *(const s8v*)&BsHi[buf][(size_t)((0 * 4 + quad) * 64 + ct * 16 + n) * 8];
      const s8v bhi1 = *(const s8v*)&BsHi[buf][(size_t)((1 * 4 + quad) * 64 + ct * 16 + n) * 8];
      const s8v blo0 = *(const s8v*)&BsLo[buf][(size_t)((0 * 4 + quad) * 64 + ct * 16 + n) * 8];
      const s8v blo1 = *(const s8v*)&BsLo[buf][(size_t)((1 * 4 + quad) * 64 + ct * 16 + n) * 8];
      const float wsn = WsS[buf][ct * 16 + n];
      const unsigned int codeT = (unsigned int)(ts * CT + ct * 16 + n);
#pragma unroll
      for (int rt = 0; rt < 2; ++rt) {
        f4v acc;
        acc[0] = hsqv4[rt][0] + wsn;
        acc[1] = hsqv4[rt][1] + wsn;
        acc[2] = hsqv4[rt][2] + wsn;
        acc[3] = hsqv4[rt][3] + wsn;
        acc = __builtin_amdgcn_mfma_f32_16x16x32_bf16(alo[rt][0], bhi0, acc, 0, 0, 0);
        acc = __builtin_amdgcn_mfma_f32_16x16x32_bf16(ahi[rt][0], blo0, acc, 0, 0, 0);
        acc = __builtin_amdgcn_mfma_f32_16x16x32_bf16(ahi[rt][0], bhi0, acc, 0, 0, 0);
        acc = __builtin_amdgcn_mfma_f32_16x16x32_bf16(alo[rt][1], bhi1, acc, 0, 0, 0);
        acc = __builtin_amdgcn_mfma_f32_16x16x32_bf16(ahi[rt][1], blo1, acc, 0, 0, 0);
        acc = __builtin_amdgcn_mfma_f32_16x16x32_bf16(ahi[rt][1], bhi1, acc, 0, 0, 0);
#pragma unroll
        for (int r = 0; r < 4; ++r) {
          const unsigned int key =
              (__float_as_uint(acc[r]) & KMASK) | codeT;     // v_and_or_b32
          // branchless 3-deep insertion via explicit u32 min/max
          const unsigned int a = umin_(m0[rt][r], key);
          const unsigned int b = umax_(m0[rt][r], key);
          m0[rt][r] = a;
          const unsigned int c = umin_(m1[rt][r], b);
          const unsigned int d = umax_(m1[rt][r], b);
          m1[rt][r] = c;
          m2[rt][r] = umin_(m2[rt][r], d);
        }
      }
    }
  }

  // ---- candidate push to global (per-half lists); local thr >= global thr
  // so over-push only (safe) ----
#pragma unroll
  for (int rt = 0; rt < 2; ++rt) {
#pragma unroll
    for (int r = 0; r < 4; ++r) {
      unsigned int km = m0[rt][r];
#pragma unroll
      for (int off = 1; off < 16; off <<= 1)
        km = umin_(km, (unsigned)__shfl_xor((int)km, off, 64));
      const float thr = __uint_as_float(km & KMASK) + MARGIN;
      const int row = rowBase + wv * 32 + rt * 16 + quad * 4 + r;
      int* cf = &cntFlag[h * N_ROWS + row];
      int* lst = &lists[(size_t)(h * N_ROWS + row) * CAPH];
      const float f0 = __uint_as_float(m0[rt][r] & KMASK);
      const float f1 = __uint_as_float(m1[rt][r] & KMASK);
      const float f2 = __uint_as_float(m2[rt][r] & KMASK);
      if (f0 <= thr) {
        const int pos = atomicAdd(cf, 1) & 0xFFFF;
        if (pos < CAPH) lst[pos] = (int)(m0[rt][r] & 0xFFFu);
        else atomicOr(cf, FLAGBIT);
      }
      if (f1 <= thr) {
        const int pos = atomicAdd(cf, 1) & 0xFFFF;
        if (pos < CAPH) lst[pos] = (int)(m1[rt][r] & 0xFFFu);
        else atomicOr(cf, FLAGBIT);
      }
      if (f2 <= thr) atomicOr(cf, FLAGBIT);  // dropped 4th could be in-margin
    }
  }
}

// ---------- merge: combine halves, exact recheck (bitwise), gather ----------
__global__ __launch_bounds__(256) void merge_kernel(
    const float* __restrict__ x, const float* __restrict__ w,
    const float* __restrict__ wsq, const float* __restrict__ hsq,
    const int* __restrict__ cntFlag, const int* __restrict__ lists,
    float* __restrict__ out, int* __restrict__ ovfCnt,
    int* __restrict__ ovfRows) {
  __shared__ int bestS[16];
  __shared__ int skipS[16];
  const int tid = threadIdx.x;
  const int rowBase = blockIdx.x * 16;

  if (tid < 16) {
    const int row = rowBase + tid;
    const int cf0 = cntFlag[row];
    const int cf1 = cntFlag[N_ROWS + row];
    const int c0v = cf0 & 0xFFFF, c1v = cf1 & 0xFFFF;
    const int nc0 = c0v < CAPH ? c0v : CAPH;
    const int nc1 = c1v < CAPH ? c1v : CAPH;
    if (((cf0 | cf1) & FLAGBIT) != 0) {
      skipS[tid] = 1;
      ovfRows[atomicAdd(ovfCnt, 1)] = row;
    } else {
      skipS[tid] = 0;
      float hv[E];
      load_row64(x + (size_t)row * E, hv);
      const float hs = hsq[row];
      float bd = INFINITY;
      int bi = 0x7FFFFFFF;
      for (int i = 0; i < nc0; ++i) {
        const int c = lists[(size_t)row * CAPH + i];
        const float d = exact_dist(hv, hs, w, wsq[c], c);
        if (d < bd || (d == bd && c < bi)) { bd = d; bi = c; }
      }
      for (int i = 0; i < nc1; ++i) {
        const int c = lists[(size_t)(N_ROWS + row) * CAPH + i];
        const float d = exact_dist(hv, hs, w, wsq[c], c);
        if (d < bd || (d == bd && c < bi)) { bd = d; bi = c; }
      }
      bestS[tid] = bi;
      out[(size_t)N_ROWS * E + row] = (float)bi;
    }
  }
  __syncthreads();
  // gather codewords: 16 threads per row, coalesced 256 B segments
  {
    const int r = tid >> 4, part = tid & 15;
    if (!skipS[r]) {
      const int bi = bestS[r];
      *(float4*)(out + (size_t)(rowBase + r) * E + part * 4) =
          *(const float4*)(w + (size_t)bi * E + part * 4);
    }
  }
}

// ---------- fallback: block-per-row, coalesced via wT, exact bitwise ---------
__global__ __launch_bounds__(256) void fallback_kernel(
    const float* __restrict__ x, const float* __restrict__ wT,
    const float* __restrict__ w, const float* __restrict__ wsq,
    const float* __restrict__ hsq, float* __restrict__ out,
    const int* __restrict__ ovfCnt, const int* __restrict__ ovfRows) {
  __shared__ float xs[E];
  __shared__ float redD[4];
  __shared__ int redI[4];
  __shared__ int bestS;
  const int tid = threadIdx.x;
  const int lane = tid & 63;
  const int wvi = tid >> 6;
  const int novf = *ovfCnt;

  for (int i = blockIdx.x; i < novf; i += gridDim.x) {
    const int row = ovfRows[i];
    if (tid < 16)
      *(float4*)&xs[tid * 4] = *(const float4*)(x + (size_t)row * E + tid * 4);
    __syncthreads();
    const float hs = hsq[row];
    float bd = INFINITY;
    int bi = 0x7FFFFFFF;
#pragma unroll 1
    for (int cc = 0; cc < 16; ++cc) {
      const int c = cc * 256 + tid;
      float dot = 0.f;
#pragma unroll
      for (int k = 0; k < E; ++k)
        dot = fmaf(wT[(size_t)k * Q + c], xs[k], dot);  // lane-contiguous
      const float d = fmaf(-2.f, dot, hs + wsq[c]);
      if (d < bd || (d == bd && c < bi)) { bd = d; bi = c; }
    }
#pragma unroll
    for (int off = 1; off < 64; off <<= 1) {
      const float od = __shfl_xor(bd, off, 64);
      const int oi = __shfl_xor(bi, off, 64);
      if (od < bd || (od == bd && oi < bi)) { bd = od; bi = oi; }
    }
    if (lane == 0) { redD[wvi] = bd; redI[wvi] = bi; }
    __syncthreads();
    if (tid == 0) {
      float fb = redD[0];
      int fi = redI[0];
#pragma unroll
      for (int t = 1; t < 4; ++t) {
        if (redD[t] < fb || (redD[t] == fb && redI[t] < fi)) {
          fb = redD[t];
          fi = redI[t];
        }
      }
      bestS = fi;
      out[(size_t)N_ROWS * E + row] = (float)fi;
    }
    __syncthreads();
    if (tid < 16) {
      const int bi2 = bestS;
      *(float4*)(out + (size_t)row * E + tid * 4) =
          *(const float4*)(w + (size_t)bi2 * E + tid * 4);
    }
    __syncthreads();
  }
}

extern "C" void kernel_launch(void* const* d_in, const int* in_sizes, int n_in,
                              void* d_out, int out_size, void* d_ws,
                              size_t ws_size, hipStream_t stream) {
  const float* x = (const float*)d_in[0];
  const float* w = (const float*)d_in[1];
  float* out = (float*)d_out;

  // ws: wsq[4096] | hsq[65536] | whiS[262144] s16 | wloS[262144] s16
  //   | wT[262144] f32 | cntFlag[131072] i32 | lists[524288] i32
  //   | ovfCnt[4] | ovfRows[65536]   (~5.6 MB)
  float* wsq = (float*)d_ws;
  float* hsq = wsq + Q;
  short* whiS = (short*)(hsq + N_ROWS);
  short* wloS = whiS + (size_t)Q * E;
  float* wT = (float*)(wloS + (size_t)Q * E);
  int* cntFlag = (int*)(wT + (size_t)Q * E);
  int* lists = cntFlag + 2 * N_ROWS;
  int* ovfCnt = lists + (size_t)2 * N_ROWS * CAPH;
  int* ovfRows = ovfCnt + 4;

  prep_kernel<<<272, 256, 0, stream>>>(w, x, wsq, hsq, whiS, wloS, wT, cntFlag,
                                       ovfCnt);
  dist_kernel<<<(N_ROWS / 128) * 2, 256, 0, stream>>>(x, whiS, wloS, wsq, hsq,
                                                      cntFlag, lists);
  merge_kernel<<<N_ROWS / 16, 256, 0, stream>>>(x, w, wsq, hsq, cntFlag, lists,
                                                out, ovfCnt, ovfRows);
  fallback_kernel<<<512, 256, 0, stream>>>(x, wT, w, wsq, hsq, out, ovfCnt,
                                           ovfRows);
}

// Round 10
// 216.827 us; speedup vs baseline: 2.0935x; 2.0935x over previous
//
#include <hip/hip_runtime.h>
#include <math.h>

#define N_ROWS 65536
#define Q 4096
#define E 64
#define CT 64                 // codes staged per tile-step
#define NTS_H 32              // tile-steps per half (2048 codes)
#define MARGIN 0.25f
#define CAPH 6                // candidate cap per (row, half)
#define CAPR 8192             // max flagged rows on the fast fallback path
#define FLAGBIT 0x40000000
#define KMASK 0xFFFFF000u

typedef short s8v __attribute__((ext_vector_type(8)));   // 8 bf16 (4 VGPRs)
typedef float f4v __attribute__((ext_vector_type(4)));   // 4 fp32 acc

static __device__ __forceinline__ unsigned umin_(unsigned a, unsigned b) {
  return __builtin_elementwise_min(a, b);   // v_min_u32
}
static __device__ __forceinline__ unsigned umax_(unsigned a, unsigned b) {
  return __builtin_elementwise_max(a, b);   // v_max_u32
}

// ---------- exact-arithmetic helpers (validated absmax=0 rounds 1-9) ----------
__device__ __forceinline__ float pairwise_sq_sum64(const float* v) {
#pragma clang fp contract(off)
  float r[8];
#pragma unroll
  for (int j = 0; j < 8; ++j) r[j] = v[j] * v[j];
#pragma unroll
  for (int i = 8; i < 64; i += 8) {
#pragma unroll
    for (int j = 0; j < 8; ++j) {
      float p = v[i + j] * v[i + j];
      r[j] = r[j] + p;
    }
  }
  return ((r[0] + r[1]) + (r[2] + r[3])) + ((r[4] + r[5]) + (r[6] + r[7]));
}

__device__ __forceinline__ void load_row64(const float* __restrict__ src,
                                           float* dst) {
  const float4* p = (const float4*)src;
#pragma unroll
  for (int k4 = 0; k4 < 16; ++k4) {
    const float4 t = p[k4];
    dst[4 * k4 + 0] = t.x;
    dst[4 * k4 + 1] = t.y;
    dst[4 * k4 + 2] = t.z;
    dst[4 * k4 + 3] = t.w;
  }
}

// exact distance, reference-bitwise: sequential fmaf k ascending,
// RN(hsq+wsq), fmaf(-2,...)
__device__ __forceinline__ float exact_dist(const float* hv, float hs,
                                            const float* __restrict__ w,
                                            float wsqc, int c) {
  const float* wr = w + (size_t)c * E;
  float dot = 0.f;
#pragma unroll
  for (int k = 0; k < E; ++k) dot = fmaf(wr[k], hv[k], dot);
  return fmaf(-2.f, dot, hs + wsqc);
}

__device__ __forceinline__ unsigned short bf16_rn(float f) {
  unsigned int u = __float_as_uint(f);
  u += 0x7FFFu + ((u >> 16) & 1u);
  return (unsigned short)(u >> 16);
}
__device__ __forceinline__ float bf16_to_f(unsigned short s) {
  return __uint_as_float(((unsigned int)s) << 16);
}

// ---------- fused prep: blocks 0..15 -> w path (+wT), 16..271 -> x path ------
__global__ __launch_bounds__(256) void prep_kernel(
    const float* __restrict__ w, const float* __restrict__ x,
    float* __restrict__ wsq, float* __restrict__ hsq,
    short* __restrict__ whiS, short* __restrict__ wloS,
    float* __restrict__ wT, int* __restrict__ cntFlag,
    int* __restrict__ ovfCnt) {
  if (blockIdx.x < 16) {
    const int q = blockIdx.x * 256 + threadIdx.x;
    if (q == 0) *ovfCnt = 0;
    float v[E];
    load_row64(w + (size_t)q * E, v);
    wsq[q] = pairwise_sq_sum64(v);
#pragma unroll
    for (int k = 0; k < E; ++k) wT[(size_t)k * Q + q] = v[k];
    const int T = q >> 6, code_in = q & 63;
#pragma unroll
    for (int ch = 0; ch < 8; ++ch) {
      s8v hi, lo;
#pragma unroll
      for (int j = 0; j < 8; ++j) {
        const float f = v[ch * 8 + j];
        const unsigned short h = bf16_rn(f);
        const float resid = f - bf16_to_f(h);
        hi[j] = (short)h;
        lo[j] = (short)bf16_rn(resid);
      }
      const size_t base = (size_t)T * 4096 + ((size_t)(ch * 64 + code_in)) * 8;
      *(s8v*)&whiS[base] = hi;
      *(s8v*)&wloS[base] = lo;
    }
  } else {
    const int n = (blockIdx.x - 16) * 256 + threadIdx.x;
    float v[E];
    load_row64(x + (size_t)n * E, v);
    hsq[n] = pairwise_sq_sum64(v);
    cntFlag[n] = 0;            // ws is re-poisoned each launch: must zero
    cntFlag[N_ROWS + n] = 0;
  }
}

// ---------- main: MFMA screen over one Q-half, packed branchless top-3 -------
// grid = 1024: block b -> rows [(b>>1)*128, +128), half h = b&1 (2048 codes).
// 4 blocks/CU (LDS 33 KB), 16 waves/CU.
__global__ __launch_bounds__(256, 4) void dist_kernel(
    const float* __restrict__ x, const short* __restrict__ whiS,
    const short* __restrict__ wloS, const float* __restrict__ wsq,
    const float* __restrict__ hsq, int* __restrict__ cntFlag,
    int* __restrict__ lists) {
  __shared__ short BsHi[2][CT * 64];   // 2 x 8 KB (double-buffered)
  __shared__ short BsLo[2][CT * 64];   // 2 x 8 KB
  __shared__ float WsS[2][CT];

  const int tid = threadIdx.x;
  const int wv = tid >> 6;
  const int lane = tid & 63;
  const int n = lane & 15;
  const int quad = lane >> 4;
  const int h = blockIdx.x & 1;
  const int rowBase = (blockIdx.x >> 1) * 128;
  const int ts0 = h * NTS_H;

  // ---- A-frags: a = -2x, split hi/lo, built once ----
  s8v ahi[2][2], alo[2][2];  // [rowtile][ks]
#pragma unroll
  for (int rt = 0; rt < 2; ++rt) {
#pragma unroll
    for (int ks = 0; ks < 2; ++ks) {
      const int gRow = rowBase + wv * 32 + rt * 16 + n;
      const float* xp = x + (size_t)gRow * E + ks * 32 + quad * 8;
      const float4 v0 = ((const float4*)xp)[0];
      const float4 v1 = ((const float4*)xp)[1];
      float vals[8] = {v0.x, v0.y, v0.z, v0.w, v1.x, v1.y, v1.z, v1.w};
      s8v hi, lo;
#pragma unroll
      for (int j = 0; j < 8; ++j) {
        const float a = -2.f * vals[j];
        const unsigned short hb = bf16_rn(a);
        hi[j] = (short)hb;
        lo[j] = (short)bf16_rn(a - bf16_to_f(hb));
      }
      ahi[rt][ks] = hi;
      alo[rt][ks] = lo;
    }
  }

  // hsq + 4.0 offset folded into C-init (keeps packed floats positive)
  float hsqv4[2][4];
#pragma unroll
  for (int rt = 0; rt < 2; ++rt)
#pragma unroll
    for (int r = 0; r < 4; ++r)
      hsqv4[rt][r] = hsq[rowBase + wv * 32 + rt * 16 + quad * 4 + r] + 4.0f;

  // branchless packed top-3 per (rowtile, r): key = (bits(d+4)&KMASK)|code
  unsigned int m0[2][4], m1[2][4], m2[2][4];
#pragma unroll
  for (int rt = 0; rt < 2; ++rt)
#pragma unroll
    for (int r = 0; r < 4; ++r) {
      m0[rt][r] = 0xFFFFFFFFu;
      m1[rt][r] = 0xFFFFFFFFu;
      m2[rt][r] = 0xFFFFFFFFu;
    }

  // ---- prefetch ts0 into registers ----
  int4 pH0, pH1, pL0, pL1;
  float pW;
  {
    const int4* gh = (const int4*)(whiS + (size_t)ts0 * 4096);
    const int4* gl = (const int4*)(wloS + (size_t)ts0 * 4096);
    pH0 = gh[tid];
    pH1 = gh[tid + 256];
    pL0 = gl[tid];
    pL1 = gl[tid + 256];
    pW = (tid < CT) ? wsq[ts0 * CT + tid] : 0.f;
  }

#pragma unroll 1
  for (int ts = ts0; ts < ts0 + NTS_H; ++ts) {
    const int buf = ts & 1;
    ((int4*)&BsHi[buf][0])[tid] = pH0;
    ((int4*)&BsHi[buf][0])[tid + 256] = pH1;
    ((int4*)&BsLo[buf][0])[tid] = pL0;
    ((int4*)&BsLo[buf][0])[tid + 256] = pL1;
    if (tid < CT) WsS[buf][tid] = pW;
    __syncthreads();  // single barrier per ts
    if (ts + 1 < ts0 + NTS_H) {
      const int4* gh = (const int4*)(whiS + (size_t)(ts + 1) * 4096);
      const int4* gl = (const int4*)(wloS + (size_t)(ts + 1) * 4096);
      pH0 = gh[tid];
      pH1 = gh[tid + 256];
      pL0 = gl[tid];
      pL1 = gl[tid + 256];
      if (tid < CT) pW = wsq[(ts + 1) * CT + tid];
    }

#pragma unroll
    for (int ct = 0; ct < 4; ++ct) {
      const s8v bhi0 = *(const s8v*)&BsHi[buf][(size_t)((0 * 4 + quad) * 64 + ct * 16 + n) * 8];
      const s8v bhi1 = *(const s8v*)&BsHi[buf][(size_t)((1 * 4 + quad) * 64 + ct * 16 + n) * 8];
      const s8v blo0 = *(const s8v*)&BsLo[buf][(size_t)((0 * 4 + quad) * 64 + ct * 16 + n) * 8];
      const s8v blo1 = *(const s8v*)&BsLo[buf][(size_t)((1 * 4 + quad) * 64 + ct * 16 + n) * 8];
      const float wsn = WsS[buf][ct * 16 + n];
      const unsigned int codeT = (unsigned int)(ts * CT + ct * 16 + n);
#pragma unroll
      for (int rt = 0; rt < 2; ++rt) {
        f4v acc;
        acc[0] = hsqv4[rt][0] + wsn;
        acc[1] = hsqv4[rt][1] + wsn;
        acc[2] = hsqv4[rt][2] + wsn;
        acc[3] = hsqv4[rt][3] + wsn;
        acc = __builtin_amdgcn_mfma_f32_16x16x32_bf16(alo[rt][0], bhi0, acc, 0, 0, 0);
        acc = __builtin_amdgcn_mfma_f32_16x16x32_bf16(ahi[rt][0], blo0, acc, 0, 0, 0);
        acc = __builtin_amdgcn_mfma_f32_16x16x32_bf16(ahi[rt][0], bhi0, acc, 0, 0, 0);
        acc = __builtin_amdgcn_mfma_f32_16x16x32_bf16(alo[rt][1], bhi1, acc, 0, 0, 0);
        acc = __builtin_amdgcn_mfma_f32_16x16x32_bf16(ahi[rt][1], blo1, acc, 0, 0, 0);
        acc = __builtin_amdgcn_mfma_f32_16x16x32_bf16(ahi[rt][1], bhi1, acc, 0, 0, 0);
#pragma unroll
        for (int r = 0; r < 4; ++r) {
          const unsigned int key =
              (__float_as_uint(acc[r]) & KMASK) | codeT;     // v_and_or_b32
          const unsigned int a = umin_(m0[rt][r], key);
          const unsigned int b = umax_(m0[rt][r], key);
          m0[rt][r] = a;
          const unsigned int c = umin_(m1[rt][r], b);
          const unsigned int d = umax_(m1[rt][r], b);
          m1[rt][r] = c;
          m2[rt][r] = umin_(m2[rt][r], d);
        }
      }
    }
  }

  // ---- candidate push to global (per-half lists); local thr >= global thr
  // so over-push only (safe) ----
#pragma unroll
  for (int rt = 0; rt < 2; ++rt) {
#pragma unroll
    for (int r = 0; r < 4; ++r) {
      unsigned int km = m0[rt][r];
#pragma unroll
      for (int off = 1; off < 16; off <<= 1)
        km = umin_(km, (unsigned)__shfl_xor((int)km, off, 64));
      const float thr = __uint_as_float(km & KMASK) + MARGIN;
      const int row = rowBase + wv * 32 + rt * 16 + quad * 4 + r;
      int* cf = &cntFlag[h * N_ROWS + row];
      int* lst = &lists[(size_t)(h * N_ROWS + row) * CAPH];
      const float f0 = __uint_as_float(m0[rt][r] & KMASK);
      const float f1 = __uint_as_float(m1[rt][r] & KMASK);
      const float f2 = __uint_as_float(m2[rt][r] & KMASK);
      if (f0 <= thr) {
        const int pos = atomicAdd(cf, 1) & 0xFFFF;
        if (pos < CAPH) lst[pos] = (int)(m0[rt][r] & 0xFFFu);
        else atomicOr(cf, FLAGBIT);
      }
      if (f1 <= thr) {
        const int pos = atomicAdd(cf, 1) & 0xFFFF;
        if (pos < CAPH) lst[pos] = (int)(m1[rt][r] & 0xFFFu);
        else atomicOr(cf, FLAGBIT);
      }
      if (f2 <= thr) atomicOr(cf, FLAGBIT);  // dropped 4th could be in-margin
    }
  }
}

// ---------- merge: combine halves, exact recheck (bitwise), gather ----------
// 256 rows per block, all 256 threads active.
__global__ __launch_bounds__(256) void merge_kernel(
    const float* __restrict__ x, const float* __restrict__ w,
    const float* __restrict__ wsq, const float* __restrict__ hsq,
    const int* __restrict__ cntFlag, const int* __restrict__ lists,
    float* __restrict__ out, int* __restrict__ ovfCnt,
    int* __restrict__ ovfRows) {
  __shared__ int bestS[256];
  const int tid = threadIdx.x;
  const int rowBase = blockIdx.x * 256;
  const int row = rowBase + tid;

  const int cf0 = cntFlag[row];
  const int cf1 = cntFlag[N_ROWS + row];
  if (((cf0 | cf1) & FLAGBIT) != 0) {
    bestS[tid] = -1;
    ovfRows[atomicAdd(ovfCnt, 1)] = row;
  } else {
    const int c0v = cf0 & 0xFFFF, c1v = cf1 & 0xFFFF;
    const int nc0 = c0v < CAPH ? c0v : CAPH;
    const int nc1 = c1v < CAPH ? c1v : CAPH;
    float hv[E];
    load_row64(x + (size_t)row * E, hv);
    const float hs = hsq[row];
    float bd = INFINITY;
    int bi = 0x7FFFFFFF;
    for (int i = 0; i < nc0; ++i) {
      const int c = lists[(size_t)row * CAPH + i];
      const float d = exact_dist(hv, hs, w, wsq[c], c);
      if (d < bd || (d == bd && c < bi)) { bd = d; bi = c; }
    }
    for (int i = 0; i < nc1; ++i) {
      const int c = lists[(size_t)(N_ROWS + row) * CAPH + i];
      const float d = exact_dist(hv, hs, w, wsq[c], c);
      if (d < bd || (d == bd && c < bi)) { bd = d; bi = c; }
    }
    bestS[tid] = bi;
    out[(size_t)N_ROWS * E + row] = (float)bi;
  }
  __syncthreads();
  // gather: 16 passes x (16 rows x 16 threads), coalesced 256 B per row
#pragma unroll 1
  for (int g = 0; g < 16; ++g) {
    const int r = g * 16 + (tid >> 4);
    const int part = tid & 15;
    const int b = bestS[r];
    if (b >= 0) {
      *(float4*)(out + (size_t)(rowBase + r) * E + part * 4) =
          *(const float4*)(w + (size_t)b * E + part * 4);
    }
  }
}

// ---------- fallback scan: one wave per (row, 256-code part) ----------------
// 4 ILP chains/lane (4 codes x 64-deep fmaf, coalesced wT loads). Exact
// lexicographic (d, c) partial per part -> pd/pc.
__global__ __launch_bounds__(256) void fallback_scan(
    const float* __restrict__ x, const float* __restrict__ wT,
    const float* __restrict__ wsq, const float* __restrict__ hsq,
    float* __restrict__ out, const float* __restrict__ w,
    const int* __restrict__ ovfCnt, const int* __restrict__ ovfRows,
    float* __restrict__ pd, int* __restrict__ pc) {
  const int novf = *ovfCnt;
  const int fastR = novf < CAPR ? novf : CAPR;
  const int lane = threadIdx.x & 63;
  const int gw = blockIdx.x * 4 + (threadIdx.x >> 6);  // 4096 waves
  const int items = fastR * 16;
  for (int j = gw; j < items; j += 4096) {
    const int row = __builtin_amdgcn_readfirstlane(ovfRows[j >> 4]);
    const int part = j & 15;
    const float* xr = x + (size_t)row * E;       // wave-uniform -> s_load
    const float hs = hsq[row];
    const float* wtp = wT + part * 256 + lane;
    float d0 = 0.f, d1 = 0.f, d2 = 0.f, d3 = 0.f;
#pragma unroll 8
    for (int k = 0; k < E; ++k) {
      const float xk = xr[k];
      d0 = fmaf(wtp[(size_t)k * Q], xk, d0);
      d1 = fmaf(wtp[(size_t)k * Q + 64], xk, d1);
      d2 = fmaf(wtp[(size_t)k * Q + 128], xk, d2);
      d3 = fmaf(wtp[(size_t)k * Q + 192], xk, d3);
    }
    float bd = INFINITY;
    int bi = 0x7FFFFFFF;
    {
      const int c = part * 256 + lane;
      const float d = fmaf(-2.f, d0, hs + wsq[c]);
      if (d < bd || (d == bd && c < bi)) { bd = d; bi = c; }
    }
    {
      const int c = part * 256 + 64 + lane;
      const float d = fmaf(-2.f, d1, hs + wsq[c]);
      if (d < bd || (d == bd && c < bi)) { bd = d; bi = c; }
    }
    {
      const int c = part * 256 + 128 + lane;
      const float d = fmaf(-2.f, d2, hs + wsq[c]);
      if (d < bd || (d == bd && c < bi)) { bd = d; bi = c; }
    }
    {
      const int c = part * 256 + 192 + lane;
      const float d = fmaf(-2.f, d3, hs + wsq[c]);
      if (d < bd || (d == bd && c < bi)) { bd = d; bi = c; }
    }
#pragma unroll
    for (int off = 1; off < 64; off <<= 1) {
      const float od = __shfl_xor(bd, off, 64);
      const int oi = __shfl_xor(bi, off, 64);
      if (od < bd || (od == bd && oi < bi)) { bd = od; bi = oi; }
    }
    if (lane == 0) { pd[j] = bd; pc[j] = bi; }
  }
  // pathological overflow (> CAPR flagged rows): slow whole-row waves
  for (int i = CAPR + gw; i < novf; i += 4096) {
    const int row = __builtin_amdgcn_readfirstlane(ovfRows[i]);
    const float* xr = x + (size_t)row * E;
    const float hs = hsq[row];
    float bd = INFINITY;
    int bi = 0x7FFFFFFF;
    for (int cc = 0; cc < 64; ++cc) {
      const int c = cc * 64 + lane;
      float dot = 0.f;
#pragma unroll 8
      for (int k = 0; k < E; ++k)
        dot = fmaf(wT[(size_t)k * Q + c], xr[k], dot);
      const float d = fmaf(-2.f, dot, hs + wsq[c]);
      if (d < bd || (d == bd && c < bi)) { bd = d; bi = c; }
    }
#pragma unroll
    for (int off = 1; off < 64; off <<= 1) {
      const float od = __shfl_xor(bd, off, 64);
      const int oi = __shfl_xor(bi, off, 64);
      if (od < bd || (od == bd && oi < bi)) { bd = od; bi = oi; }
    }
    if (lane == 0) out[(size_t)N_ROWS * E + row] = (float)bi;
    out[(size_t)row * E + lane] = w[(size_t)bi * E + lane];
  }
}

// ---------- fallback finalize: reduce 16 parts/row, write idx + gather -------
__global__ __launch_bounds__(256) void fallback_finalize(
    const float* __restrict__ w, float* __restrict__ out,
    const int* __restrict__ ovfCnt, const int* __restrict__ ovfRows,
    const float* __restrict__ pd, const int* __restrict__ pc) {
  __shared__ int bestS[16];
  const int novf0 = *ovfCnt;
  const int fastR = novf0 < CAPR ? novf0 : CAPR;
  const int tid = threadIdx.x;
#pragma unroll 1
  for (int base = blockIdx.x * 16; base < fastR; base += gridDim.x * 16) {
    const int i = base + (tid >> 4);
    const int part = tid & 15;
    if (i < fastR && part == 0) {
      float bd = INFINITY;
      int bi = 0x7FFFFFFF;
#pragma unroll 1
      for (int p = 0; p < 16; ++p) {
        const float d = pd[i * 16 + p];
        const int c = pc[i * 16 + p];
        if (d < bd || (d == bd && c < bi)) { bd = d; bi = c; }
      }
      bestS[tid >> 4] = bi;
      out[(size_t)N_ROWS * E + ovfRows[i]] = (float)bi;
    }
    __syncthreads();
    if (i < fastR) {
      const int row = ovfRows[i];
      const int b = bestS[tid >> 4];
      *(float4*)(out + (size_t)row * E + part * 4) =
          *(const float4*)(w + (size_t)b * E + part * 4);
    }
    __syncthreads();
  }
}

extern "C" void kernel_launch(void* const* d_in, const int* in_sizes, int n_in,
                              void* d_out, int out_size, void* d_ws,
                              size_t ws_size, hipStream_t stream) {
  const float* x = (const float*)d_in[0];
  const float* w = (const float*)d_in[1];
  float* out = (float*)d_out;

  // ws layout (~7.1 MB): wsq[4096] | hsq[65536] | whiS | wloS | wT
  //   | cntFlag[2*N] | lists[2*N*CAPH] | ovfCnt[4] | ovfRows[N]
  //   | pd[CAPR*16] f32 | pc[CAPR*16] i32
  float* wsq = (float*)d_ws;
  float* hsq = wsq + Q;
  short* whiS = (short*)(hsq + N_ROWS);
  short* wloS = whiS + (size_t)Q * E;
  float* wT = (float*)(wloS + (size_t)Q * E);
  int* cntFlag = (int*)(wT + (size_t)Q * E);
  int* lists = cntFlag + 2 * N_ROWS;
  int* ovfCnt = lists + (size_t)2 * N_ROWS * CAPH;
  int* ovfRows = ovfCnt + 4;
  float* pd = (float*)(ovfRows + N_ROWS);
  int* pc = (int*)(pd + (size_t)CAPR * 16);

  prep_kernel<<<272, 256, 0, stream>>>(w, x, wsq, hsq, whiS, wloS, wT, cntFlag,
                                       ovfCnt);
  dist_kernel<<<(N_ROWS / 128) * 2, 256, 0, stream>>>(x, whiS, wloS, wsq, hsq,
                                                      cntFlag, lists);
  merge_kernel<<<N_ROWS / 256, 256, 0, stream>>>(x, w, wsq, hsq, cntFlag, lists,
                                                 out, ovfCnt, ovfRows);
  fallback_scan<<<1024, 256, 0, stream>>>(x, wT, wsq, hsq, out, w, ovfCnt,
                                          ovfRows, pd, pc);
  fallback_finalize<<<256, 256, 0, stream>>>(w, out, ovfCnt, ovfRows, pd, pc);
}